// Round 2
// baseline (517.016 us; speedup 1.0000x reference)
//
#include <hip/hip_runtime.h>
#include <hip/hip_bf16.h>
#include <stdint.h>

#define DIM    1024
#define NHEAD  16
#define HD     64
#define MAXREL 256
#define BB     4
#define SS     2048
#define MM     (BB*SS)     // 8192 rows

typedef float f32x4 __attribute__((ext_vector_type(4)));
typedef short s16x8 __attribute__((ext_vector_type(8)));

__device__ __forceinline__ ushort f2bf(float f) {
  union { float f; uint32_t u; } v; v.f = f;
  uint32_t r = v.u + 0x7FFFu + ((v.u >> 16) & 1u);   // RNE
  return (ushort)(r >> 16);
}

__global__ void cast_kernel(const float* __restrict__ in, ushort* __restrict__ out, int n4) {
  int i = blockIdx.x * blockDim.x + threadIdx.x;
  if (i < n4) {
    float4 v = reinterpret_cast<const float4*>(in)[i];
    ushort4 o; o.x = f2bf(v.x); o.y = f2bf(v.y); o.z = f2bf(v.z); o.w = f2bf(v.w);
    reinterpret_cast<ushort4*>(out)[i] = o;
  }
}

// 4 weight matrices (each DIM*DIM), outputs contiguous. n4each = DIM*DIM/4 = 2^18.
__global__ void cast4_kernel(const float* __restrict__ w0, const float* __restrict__ w1,
                             const float* __restrict__ w2, const float* __restrict__ w3,
                             ushort* __restrict__ out) {
  int i = blockIdx.x * blockDim.x + threadIdx.x;   // 0 .. 4*2^18-1
  int which = i >> 18;
  int j = i & ((1 << 18) - 1);
  const float* src = (which == 0) ? w0 : (which == 1) ? w1 : (which == 2) ? w2 : w3;
  float4 v = reinterpret_cast<const float4*>(src)[j];
  ushort4 o; o.x = f2bf(v.x); o.y = f2bf(v.y); o.z = f2bf(v.z); o.w = f2bf(v.w);
  reinterpret_cast<ushort4*>(out)[i] = o;
}

// C = A[M,K] * W[N,K]^T + bias.  mode 0: bf16 out [b*16+h][s][64] (Q/K layout)
// mode 2: bf16 out [b*16+h][64][s] (V^T layout).  mode 3: f32 out row-major [M][N].
__global__ __launch_bounds__(256) void gemm_bt(
    const ushort* __restrict__ A, const ushort* __restrict__ W,
    const float* __restrict__ bias, void* __restrict__ out, int mode) {
  __shared__ ushort At[128 * 64];
  __shared__ ushort Bt[128 * 64];
  const int tid = threadIdx.x;
  const int lane = tid & 63, w = tid >> 6;
  const int g = lane >> 4, c16 = lane & 15;
  const int ln8 = lane >> 3, l8 = lane & 7;
  const int m0 = blockIdx.y * 128, n0 = blockIdx.x * 128;
  const int wm = w >> 1, wn = w & 1;
  const int slotp = l8 ^ ln8;   // pre-swizzled global 16B-slot (m173 pattern)

  f32x4 acc[4][4];
#pragma unroll
  for (int i = 0; i < 4; i++)
#pragma unroll
    for (int j = 0; j < 4; j++) acc[i][j] = f32x4{0.f, 0.f, 0.f, 0.f};

  for (int k0 = 0; k0 < DIM; k0 += 64) {
    __syncthreads();
#pragma unroll
    for (int t = 0; t < 4; t++) {
      int seg = w * 4 + t;                       // 8 rows per seg
      const ushort* ga = A + (size_t)(m0 + seg * 8 + ln8) * DIM + k0 + slotp * 8;
      __builtin_amdgcn_global_load_lds((const __attribute__((address_space(1))) void*)ga,
          (__attribute__((address_space(3))) void*)(At + seg * 512), 16, 0, 0);
      const ushort* gb = W + (size_t)(n0 + seg * 8 + ln8) * DIM + k0 + slotp * 8;
      __builtin_amdgcn_global_load_lds((const __attribute__((address_space(1))) void*)gb,
          (__attribute__((address_space(3))) void*)(Bt + seg * 512), 16, 0, 0);
    }
    __syncthreads();

#pragma unroll
    for (int kk = 0; kk < 2; kk++) {
      s16x8 af[4], bfr[4];
#pragma unroll
      for (int mi = 0; mi < 4; mi++) {
        int row = wm * 64 + mi * 16 + c16;
        int slot = (kk * 4 + g) ^ (row & 7);
        af[mi] = *(const s16x8*)(At + row * 64 + slot * 8);
      }
#pragma unroll
      for (int ni = 0; ni < 4; ni++) {
        int row = wn * 64 + ni * 16 + c16;
        int slot = (kk * 4 + g) ^ (row & 7);
        bfr[ni] = *(const s16x8*)(Bt + row * 64 + slot * 8);
      }
#pragma unroll
      for (int mi = 0; mi < 4; mi++)
#pragma unroll
        for (int ni = 0; ni < 4; ni++)
          acc[mi][ni] = __builtin_amdgcn_mfma_f32_16x16x32_bf16(af[mi], bfr[ni], acc[mi][ni], 0, 0, 0);
    }
  }

#pragma unroll
  for (int mi = 0; mi < 4; mi++)
#pragma unroll
    for (int ni = 0; ni < 4; ni++)
#pragma unroll
      for (int r = 0; r < 4; r++) {
        int m = m0 + wm * 64 + mi * 16 + g * 4 + r;   // D row = (lane>>4)*4 + reg
        int n = n0 + wn * 64 + ni * 16 + c16;         // D col = lane&15
        float v = acc[mi][ni][r] + bias[n];
        if (mode == 3) {
          ((float*)out)[(size_t)m * DIM + n] = v;
        } else {
          int b = m >> 11, s = m & 2047;
          int h = n >> 6,  d = n & 63;
          ushort bv = f2bf(v);
          if (mode == 0)
            ((ushort*)out)[((size_t)(b * NHEAD + h) * SS + s) * HD + d] = bv;
          else
            ((ushort*)out)[((size_t)(b * NHEAD + h) * HD + d) * SS + s] = bv;
        }
      }
}

// Flash attention: block = 64 q-rows of one (b,h); 4 waves x 16 q-rows.
__global__ __launch_bounds__(256) void attn_kernel(
    const ushort* __restrict__ Qb, const ushort* __restrict__ Kb,
    const ushort* __restrict__ Vt, const float* __restrict__ relb,
    ushort* __restrict__ Ob) {
  __shared__ ushort Kt[64 * 64];
  __shared__ ushort Vtile[64 * 64];
  __shared__ ushort Pt[4][16 * 128];   // per-wave P transpose buffer [16 q][128 (64 used)]
  const int tid = threadIdx.x;
  const int lane = tid & 63, w = tid >> 6;
  const int g = lane >> 4, c16 = lane & 15;
  const int ln8 = lane >> 3, l8 = lane & 7;
  const int bh = blockIdx.y, h = bh & 15, b = bh >> 4;
  const int qw = blockIdx.x * 64 + w * 16;
  const size_t bhoff = (size_t)bh * SS * HD;
  const int slotp = l8 ^ ln8;

  s16x8 aq[2];
  aq[0] = *(const s16x8*)(Qb + bhoff + (size_t)(qw + c16) * HD + g * 8);
  aq[1] = *(const s16x8*)(Qb + bhoff + (size_t)(qw + c16) * HD + 32 + g * 8);

  f32x4 oacc[4];
#pragma unroll
  for (int i = 0; i < 4; i++) oacc[i] = f32x4{0.f, 0.f, 0.f, 0.f};
  float mrow[4], lrow[4];
#pragma unroll
  for (int r = 0; r < 4; r++) { mrow[r] = -3.0e38f; lrow[r] = 0.f; }

  ushort* pw = &Pt[w][0];

  for (int kb = 0; kb < 32; kb++) {
    __syncthreads();
#pragma unroll
    for (int t = 0; t < 2; t++) {
      int seg = w * 2 + t;
      const ushort* gk = Kb + bhoff + (size_t)(kb * 64 + seg * 8 + ln8) * HD + slotp * 8;
      __builtin_amdgcn_global_load_lds((const __attribute__((address_space(1))) void*)gk,
          (__attribute__((address_space(3))) void*)(Kt + seg * 512), 16, 0, 0);
      const ushort* gv = Vt + bhoff + (size_t)(seg * 8 + ln8) * SS + kb * 64 + slotp * 8;
      __builtin_amdgcn_global_load_lds((const __attribute__((address_space(1))) void*)gv,
          (__attribute__((address_space(3))) void*)(Vtile + seg * 512), 16, 0, 0);
    }
    __syncthreads();

    // scores: S[16 q][64 keys] per wave, as 4 col-fragments
    f32x4 sc[4];
#pragma unroll
    for (int cj = 0; cj < 4; cj++) {
      f32x4 z = f32x4{0.f, 0.f, 0.f, 0.f};
#pragma unroll
      for (int kk = 0; kk < 2; kk++) {
        int row = cj * 16 + c16;
        int slot = (kk * 4 + g) ^ (row & 7);
        s16x8 bk = *(const s16x8*)(Kt + row * 64 + slot * 8);
        z = __builtin_amdgcn_mfma_f32_16x16x32_bf16(aq[kk], bk, z, 0, 0, 0);
      }
      sc[cj] = z;
    }
    // scale + relative position bias
#pragma unroll
    for (int cj = 0; cj < 4; cj++) {
      int key = kb * 64 + cj * 16 + c16;
#pragma unroll
      for (int r = 0; r < 4; r++) {
        int q = qw + g * 4 + r;
        int rel = q - key;
        rel = (rel < -MAXREL) ? -MAXREL : (rel > MAXREL ? MAXREL : rel);
        sc[cj][r] = sc[cj][r] * 0.125f + relb[(rel + MAXREL) * NHEAD + h];
      }
    }
    // online softmax (row stats live in lanes owning D rows g*4+r)
#pragma unroll
    for (int r = 0; r < 4; r++) {
      float mx = fmaxf(fmaxf(sc[0][r], sc[1][r]), fmaxf(sc[2][r], sc[3][r]));
      mx = fmaxf(mx, __shfl_xor(mx, 1));
      mx = fmaxf(mx, __shfl_xor(mx, 2));
      mx = fmaxf(mx, __shfl_xor(mx, 4));
      mx = fmaxf(mx, __shfl_xor(mx, 8));
      float mn = fmaxf(mrow[r], mx);
      float alpha = __expf(mrow[r] - mn);
      mrow[r] = mn;
#pragma unroll
      for (int ni = 0; ni < 4; ni++) oacc[ni][r] *= alpha;
      float rs = 0.f;
#pragma unroll
      for (int cj = 0; cj < 4; cj++) {
        float p = __expf(sc[cj][r] - mn);
        sc[cj][r] = p; rs += p;
      }
      rs += __shfl_xor(rs, 1); rs += __shfl_xor(rs, 2);
      rs += __shfl_xor(rs, 4); rs += __shfl_xor(rs, 8);
      lrow[r] = lrow[r] * alpha + rs;
    }
    // P (D-layout) -> LDS (A-layout), XOR-swizzled rows of 128 elems
#pragma unroll
    for (int cj = 0; cj < 4; cj++)
#pragma unroll
      for (int r = 0; r < 4; r++) {
        int prow = g * 4 + r, pcol = cj * 16 + c16;
        pw[prow * 128 + (pcol ^ ((prow & 7) << 3))] = f2bf(sc[cj][r]);
      }
    // PV: A = P[16 q][32 k], B = V^T rows (col=d, k-run=keys)
#pragma unroll
    for (int kk = 0; kk < 2; kk++) {
      s16x8 ap = *(const s16x8*)(pw + c16 * 128 + ((kk * 32 + g * 8) ^ ((c16 & 7) << 3)));
#pragma unroll
      for (int ni = 0; ni < 4; ni++) {
        int row = ni * 16 + c16;               // d index
        int slot = (kk * 4 + g) ^ (row & 7);
        s16x8 bv = *(const s16x8*)(Vtile + row * 64 + slot * 8);
        oacc[ni] = __builtin_amdgcn_mfma_f32_16x16x32_bf16(ap, bv, oacc[ni], 0, 0, 0);
      }
    }
  }

#pragma unroll
  for (int r = 0; r < 4; r++) mrow[r] = 1.f / lrow[r];   // reuse as inv
#pragma unroll
  for (int ni = 0; ni < 4; ni++)
#pragma unroll
    for (int r = 0; r < 4; r++) {
      int q = qw + g * 4 + r;
      int col = h * 64 + ni * 16 + c16;
      Ob[(size_t)(b * SS + q) * DIM + col] = f2bf(oacc[ni][r] * mrow[r]);
    }
}

extern "C" void kernel_launch(void* const* d_in, const int* in_sizes, int n_in,
                              void* d_out, int out_size, void* d_ws, size_t ws_size,
                              hipStream_t stream) {
  const float* x  = (const float*)d_in[0];
  const float* Wq = (const float*)d_in[1];
  const float* bq = (const float*)d_in[2];
  const float* Wk = (const float*)d_in[3];
  const float* bk = (const float*)d_in[4];
  const float* Wv = (const float*)d_in[5];
  const float* bv = (const float*)d_in[6];
  const float* Wo = (const float*)d_in[7];
  const float* bo = (const float*)d_in[8];
  const float* relb = (const float*)d_in[9];

  uint8_t* ws = (uint8_t*)d_ws;
  ushort* x_bf   = (ushort*)(ws + 0);                    // 16 MB
  ushort* wq_bf  = (ushort*)(ws + (16u << 20));          // 2 MB each, contiguous
  ushort* wk_bf  = (ushort*)(ws + (18u << 20));
  ushort* wv_bf  = (ushort*)(ws + (20u << 20));
  ushort* wo_bf  = (ushort*)(ws + (22u << 20));
  ushort* q_bf   = (ushort*)(ws + (24u << 20));          // 16 MB
  ushort* k_bf   = (ushort*)(ws + (40u << 20));          // 16 MB
  ushort* vt_bf  = (ushort*)(ws + (56u << 20));          // 16 MB
  ushort* at_bf  = (ushort*)(ws + (72u << 20));          // 16 MB

  const int NX = MM * DIM / 4;       // 2097152
  cast_kernel<<<NX / 256, 256, 0, stream>>>(x, x_bf, NX);
  cast4_kernel<<<(4 << 18) / 256, 256, 0, stream>>>(Wq, Wk, Wv, Wo, wq_bf);

  dim3 gg(DIM / 128, MM / 128);
  gemm_bt<<<gg, 256, 0, stream>>>(x_bf, wq_bf, bq, q_bf, 0);
  gemm_bt<<<gg, 256, 0, stream>>>(x_bf, wk_bf, bk, k_bf, 0);
  gemm_bt<<<gg, 256, 0, stream>>>(x_bf, wv_bf, bv, vt_bf, 2);

  attn_kernel<<<dim3(SS / 64, BB * NHEAD), 256, 0, stream>>>(q_bf, k_bf, vt_bf, relb, at_bf);

  gemm_bt<<<gg, 256, 0, stream>>>(at_bf, wo_bf, bo, d_out, 3);
}

// Round 6
// 437.685 us; speedup vs baseline: 1.1813x; 1.1813x over previous
//
#include <hip/hip_runtime.h>
#include <hip/hip_bf16.h>
#include <stdint.h>

#define DIM    1024
#define NHEAD  16
#define HD     64
#define MAXREL 256
#define BB     4
#define SS     2048
#define MM     (BB*SS)     // 8192 rows

typedef float f32x4 __attribute__((ext_vector_type(4)));
typedef short s16x8 __attribute__((ext_vector_type(8)));

__device__ __forceinline__ ushort f2bf(float f) {
  union { float f; uint32_t u; } v; v.f = f;
  uint32_t r = v.u + 0x7FFFu + ((v.u >> 16) & 1u);   // RNE
  return (ushort)(r >> 16);
}

__device__ __forceinline__ ushort f2bf_hw(float f) {
  __hip_bfloat16 h = __float2bfloat16(f);
  return *reinterpret_cast<ushort*>(&h);
}

__global__ void cast_kernel(const float* __restrict__ in, ushort* __restrict__ out, int n4) {
  int i = blockIdx.x * blockDim.x + threadIdx.x;
  if (i < n4) {
    float4 v = reinterpret_cast<const float4*>(in)[i];
    ushort4 o; o.x = f2bf(v.x); o.y = f2bf(v.y); o.z = f2bf(v.z); o.w = f2bf(v.w);
    reinterpret_cast<ushort4*>(out)[i] = o;
  }
}

// 4 weight matrices (each DIM*DIM), outputs contiguous. n4each = DIM*DIM/4 = 2^18.
__global__ void cast4_kernel(const float* __restrict__ w0, const float* __restrict__ w1,
                             const float* __restrict__ w2, const float* __restrict__ w3,
                             ushort* __restrict__ out) {
  int i = blockIdx.x * blockDim.x + threadIdx.x;   // 0 .. 4*2^18-1
  int which = i >> 18;
  int j = i & ((1 << 18) - 1);
  const float* src = (which == 0) ? w0 : (which == 1) ? w1 : (which == 2) ? w2 : w3;
  float4 v = reinterpret_cast<const float4*>(src)[j];
  ushort4 o; o.x = f2bf(v.x); o.y = f2bf(v.y); o.z = f2bf(v.z); o.w = f2bf(v.w);
  reinterpret_cast<ushort4*>(out)[i] = o;
}

// Fused QKV projection: C = x[M,1024] * Wqkv[3072,1024]^T + bias, epilogue scatters
// per 1024-col segment: seg0 -> Q [bh][s][64], seg1 -> K [bh][s][64], seg2 -> V^T [bh][64][s].
__global__ __launch_bounds__(256) void gemm_qkv(
    const ushort* __restrict__ A, const ushort* __restrict__ W,
    const float* __restrict__ bq, const float* __restrict__ bk, const float* __restrict__ bv,
    ushort* __restrict__ Qo, ushort* __restrict__ Ko, ushort* __restrict__ Vto) {
  __shared__ ushort At[128 * 64];
  __shared__ ushort Bt[128 * 64];
  const int tid = threadIdx.x;
  const int lane = tid & 63, w = tid >> 6;
  const int g = lane >> 4, c16 = lane & 15;
  const int ln8 = lane >> 3, l8 = lane & 7;
  const int m0 = blockIdx.y * 128, n0 = blockIdx.x * 128;
  const int wm = w >> 1, wn = w & 1;
  const int slotp = l8 ^ ln8;

  f32x4 acc[4][4];
#pragma unroll
  for (int i = 0; i < 4; i++)
#pragma unroll
    for (int j = 0; j < 4; j++) acc[i][j] = f32x4{0.f, 0.f, 0.f, 0.f};

  for (int k0 = 0; k0 < DIM; k0 += 64) {
    __syncthreads();
#pragma unroll
    for (int t = 0; t < 4; t++) {
      int seg = w * 4 + t;
      const ushort* ga = A + (size_t)(m0 + seg * 8 + ln8) * DIM + k0 + slotp * 8;
      __builtin_amdgcn_global_load_lds((const __attribute__((address_space(1))) void*)ga,
          (__attribute__((address_space(3))) void*)(At + seg * 512), 16, 0, 0);
      const ushort* gb = W + (size_t)(n0 + seg * 8 + ln8) * DIM + k0 + slotp * 8;
      __builtin_amdgcn_global_load_lds((const __attribute__((address_space(1))) void*)gb,
          (__attribute__((address_space(3))) void*)(Bt + seg * 512), 16, 0, 0);
    }
    __syncthreads();

#pragma unroll
    for (int kk = 0; kk < 2; kk++) {
      s16x8 af[4], bfr[4];
#pragma unroll
      for (int mi = 0; mi < 4; mi++) {
        int row = wm * 64 + mi * 16 + c16;
        int slot = (kk * 4 + g) ^ (row & 7);
        af[mi] = *(const s16x8*)(At + row * 64 + slot * 8);
      }
#pragma unroll
      for (int ni = 0; ni < 4; ni++) {
        int row = wn * 64 + ni * 16 + c16;
        int slot = (kk * 4 + g) ^ (row & 7);
        bfr[ni] = *(const s16x8*)(Bt + row * 64 + slot * 8);
      }
#pragma unroll
      for (int mi = 0; mi < 4; mi++)
#pragma unroll
        for (int ni = 0; ni < 4; ni++)
          acc[mi][ni] = __builtin_amdgcn_mfma_f32_16x16x32_bf16(af[mi], bfr[ni], acc[mi][ni], 0, 0, 0);
    }
  }

  const int which = n0 >> 10;                  // block-uniform (128 | 1024)
  const float* bp = (which == 0) ? bq : (which == 1) ? bk : bv;
  ushort* qk = (which == 0) ? Qo : Ko;
#pragma unroll
  for (int mi = 0; mi < 4; mi++)
#pragma unroll
    for (int ni = 0; ni < 4; ni++)
#pragma unroll
      for (int r = 0; r < 4; r++) {
        int m = m0 + wm * 64 + mi * 16 + g * 4 + r;
        int n = n0 + wn * 64 + ni * 16 + c16;
        int col = n & 1023;
        float v = acc[mi][ni][r] + bp[col];
        int b = m >> 11, s = m & 2047;
        int h = col >> 6, d = col & 63;
        ushort bv16 = f2bf(v);
        if (which < 2)
          qk[((size_t)(b * NHEAD + h) * SS + s) * HD + d] = bv16;
        else
          Vto[((size_t)(b * NHEAD + h) * HD + d) * SS + s] = bv16;
      }
}

// Output projection: C = A[M,K] * W[N,K]^T + bias -> f32 row-major [M][N].
__global__ __launch_bounds__(256) void gemm_bt(
    const ushort* __restrict__ A, const ushort* __restrict__ W,
    const float* __restrict__ bias, float* __restrict__ out) {
  __shared__ ushort At[128 * 64];
  __shared__ ushort Bt[128 * 64];
  const int tid = threadIdx.x;
  const int lane = tid & 63, w = tid >> 6;
  const int g = lane >> 4, c16 = lane & 15;
  const int ln8 = lane >> 3, l8 = lane & 7;
  const int m0 = blockIdx.y * 128, n0 = blockIdx.x * 128;
  const int wm = w >> 1, wn = w & 1;
  const int slotp = l8 ^ ln8;

  f32x4 acc[4][4];
#pragma unroll
  for (int i = 0; i < 4; i++)
#pragma unroll
    for (int j = 0; j < 4; j++) acc[i][j] = f32x4{0.f, 0.f, 0.f, 0.f};

  for (int k0 = 0; k0 < DIM; k0 += 64) {
    __syncthreads();
#pragma unroll
    for (int t = 0; t < 4; t++) {
      int seg = w * 4 + t;
      const ushort* ga = A + (size_t)(m0 + seg * 8 + ln8) * DIM + k0 + slotp * 8;
      __builtin_amdgcn_global_load_lds((const __attribute__((address_space(1))) void*)ga,
          (__attribute__((address_space(3))) void*)(At + seg * 512), 16, 0, 0);
      const ushort* gb = W + (size_t)(n0 + seg * 8 + ln8) * DIM + k0 + slotp * 8;
      __builtin_amdgcn_global_load_lds((const __attribute__((address_space(1))) void*)gb,
          (__attribute__((address_space(3))) void*)(Bt + seg * 512), 16, 0, 0);
    }
    __syncthreads();

#pragma unroll
    for (int kk = 0; kk < 2; kk++) {
      s16x8 af[4], bfr[4];
#pragma unroll
      for (int mi = 0; mi < 4; mi++) {
        int row = wm * 64 + mi * 16 + c16;
        int slot = (kk * 4 + g) ^ (row & 7);
        af[mi] = *(const s16x8*)(At + row * 64 + slot * 8);
      }
#pragma unroll
      for (int ni = 0; ni < 4; ni++) {
        int row = wn * 64 + ni * 16 + c16;
        int slot = (kk * 4 + g) ^ (row & 7);
        bfr[ni] = *(const s16x8*)(Bt + row * 64 + slot * 8);
      }
#pragma unroll
      for (int mi = 0; mi < 4; mi++)
#pragma unroll
        for (int ni = 0; ni < 4; ni++)
          acc[mi][ni] = __builtin_amdgcn_mfma_f32_16x16x32_bf16(af[mi], bfr[ni], acc[mi][ni], 0, 0, 0);
    }
  }

#pragma unroll
  for (int mi = 0; mi < 4; mi++)
#pragma unroll
    for (int ni = 0; ni < 4; ni++)
#pragma unroll
      for (int r = 0; r < 4; r++) {
        int m = m0 + wm * 64 + mi * 16 + g * 4 + r;
        int n = n0 + wn * 64 + ni * 16 + c16;
        out[(size_t)m * DIM + n] = acc[mi][ni][r] + bias[n];
      }
}

// Flash attention: flat grid, XCD-grouped so all 32 q-blocks of one (b,h) share an XCD.
// Block = 64 q-rows of one (b,h); 4 waves x 16 q-rows.
__global__ __launch_bounds__(256) void attn_kernel(
    const ushort* __restrict__ Qb, const ushort* __restrict__ Kb,
    const ushort* __restrict__ Vt, const float* __restrict__ relb,
    ushort* __restrict__ Ob) {
  __shared__ ushort Kt[64 * 64];
  __shared__ ushort Vtile[64 * 64];
  __shared__ ushort Pt[4][16 * 64];     // per-wave P transpose buffer [16 q][64]
  __shared__ float btab[516];           // per-head rel bias table
  const int tid = threadIdx.x;
  const int lane = tid & 63, w = tid >> 6;
  const int g = lane >> 4, c16 = lane & 15;
  const int ln8 = lane >> 3, l8 = lane & 7;

  // XCD-grouped decode: xcd = bid&7 (round-robin dispatch), 8 bh per xcd.
  const int bid = blockIdx.x;
  const int idx = bid >> 3;
  const int bh = (bid & 7) * 8 + (idx & 7);
  const int qb = idx >> 3;              // 0..31
  const int h = bh & 15, b = bh >> 4;
  const int qw = qb * 64 + w * 16;
  const size_t bhoff = (size_t)bh * SS * HD;
  const int slotp = l8 ^ ln8;

  for (int j = tid; j < 513; j += 256) btab[j] = relb[j * NHEAD + h];

  s16x8 aq[2];
  aq[0] = *(const s16x8*)(Qb + bhoff + (size_t)(qw + c16) * HD + g * 8);
  aq[1] = *(const s16x8*)(Qb + bhoff + (size_t)(qw + c16) * HD + 32 + g * 8);

  f32x4 oacc[4];
#pragma unroll
  for (int i = 0; i < 4; i++) oacc[i] = f32x4{0.f, 0.f, 0.f, 0.f};
  float mrow[4], lrow[4];
#pragma unroll
  for (int r = 0; r < 4; r++) { mrow[r] = -3.0e38f; lrow[r] = 0.f; }

  ushort* pw = &Pt[w][0];

  for (int kb = 0; kb < 32; kb++) {
    __syncthreads();
#pragma unroll
    for (int t = 0; t < 2; t++) {
      int seg = w * 2 + t;
      const ushort* gk = Kb + bhoff + (size_t)(kb * 64 + seg * 8 + ln8) * HD + slotp * 8;
      __builtin_amdgcn_global_load_lds((const __attribute__((address_space(1))) void*)gk,
          (__attribute__((address_space(3))) void*)(Kt + seg * 512), 16, 0, 0);
      const ushort* gv = Vt + bhoff + (size_t)(seg * 8 + ln8) * SS + kb * 64 + slotp * 8;
      __builtin_amdgcn_global_load_lds((const __attribute__((address_space(1))) void*)gv,
          (__attribute__((address_space(3))) void*)(Vtile + seg * 512), 16, 0, 0);
    }
    __syncthreads();

    // scores: S[16 q][64 keys] per wave, as 4 col-fragments
    f32x4 sc[4];
    __builtin_amdgcn_s_setprio(1);
#pragma unroll
    for (int cj = 0; cj < 4; cj++) {
      f32x4 z = f32x4{0.f, 0.f, 0.f, 0.f};
#pragma unroll
      for (int kk = 0; kk < 2; kk++) {
        int row = cj * 16 + c16;
        int slot = (kk * 4 + g) ^ (row & 7);
        s16x8 bk = *(const s16x8*)(Kt + row * 64 + slot * 8);
        z = __builtin_amdgcn_mfma_f32_16x16x32_bf16(aq[kk], bk, z, 0, 0, 0);
      }
      sc[cj] = z;
    }
    __builtin_amdgcn_s_setprio(0);

    // scale + relative position bias from LDS table
#pragma unroll
    for (int cj = 0; cj < 4; cj++) {
      int relbase = qw + g * 4 - (kb * 64 + cj * 16 + c16);   // + r
#pragma unroll
      for (int r = 0; r < 4; r++) {
        int rel = relbase + r;
        rel = (rel < -MAXREL) ? -MAXREL : (rel > MAXREL ? MAXREL : rel);
        sc[cj][r] = sc[cj][r] * 0.125f + btab[rel + MAXREL];
      }
    }
    // online softmax (row stats live in lanes owning D rows g*4+r)
#pragma unroll
    for (int r = 0; r < 4; r++) {
      float mx = fmaxf(fmaxf(sc[0][r], sc[1][r]), fmaxf(sc[2][r], sc[3][r]));
      mx = fmaxf(mx, __shfl_xor(mx, 1));
      mx = fmaxf(mx, __shfl_xor(mx, 2));
      mx = fmaxf(mx, __shfl_xor(mx, 4));
      mx = fmaxf(mx, __shfl_xor(mx, 8));
      float mn = fmaxf(mrow[r], mx);
      float alpha = __expf(mrow[r] - mn);
      mrow[r] = mn;
#pragma unroll
      for (int ni = 0; ni < 4; ni++) oacc[ni][r] *= alpha;
      float rs = 0.f;
#pragma unroll
      for (int cj = 0; cj < 4; cj++) {
        float p = __expf(sc[cj][r] - mn);
        sc[cj][r] = p; rs += p;
      }
      rs += __shfl_xor(rs, 1); rs += __shfl_xor(rs, 2);
      rs += __shfl_xor(rs, 4); rs += __shfl_xor(rs, 8);
      lrow[r] = lrow[r] * alpha + rs;
    }
    // P (D-layout) -> LDS (A-layout), XOR-swizzled rows of 64 elems
#pragma unroll
    for (int cj = 0; cj < 4; cj++)
#pragma unroll
      for (int r = 0; r < 4; r++) {
        int prow = g * 4 + r, pcol = cj * 16 + c16;
        pw[prow * 64 + (pcol ^ ((prow & 7) << 3))] = f2bf_hw(sc[cj][r]);
      }
    // PV: A = P[16 q][32 k], B = V^T rows (col=d, k-run=keys)
    __builtin_amdgcn_s_setprio(1);
#pragma unroll
    for (int kk = 0; kk < 2; kk++) {
      s16x8 ap = *(const s16x8*)(pw + c16 * 64 + ((kk * 32 + g * 8) ^ ((c16 & 7) << 3)));
#pragma unroll
      for (int ni = 0; ni < 4; ni++) {
        int row = ni * 16 + c16;               // d index
        int slot = (kk * 4 + g) ^ (row & 7);
        s16x8 bv = *(const s16x8*)(Vtile + row * 64 + slot * 8);
        oacc[ni] = __builtin_amdgcn_mfma_f32_16x16x32_bf16(ap, bv, oacc[ni], 0, 0, 0);
      }
    }
    __builtin_amdgcn_s_setprio(0);
  }

#pragma unroll
  for (int r = 0; r < 4; r++) mrow[r] = 1.f / lrow[r];   // reuse as inv
#pragma unroll
  for (int ni = 0; ni < 4; ni++)
#pragma unroll
    for (int r = 0; r < 4; r++) {
      int q = qw + g * 4 + r;
      int col = h * 64 + ni * 16 + c16;
      Ob[(size_t)(b * SS + q) * DIM + col] = f2bf_hw(oacc[ni][r] * mrow[r]);
    }
}

extern "C" void kernel_launch(void* const* d_in, const int* in_sizes, int n_in,
                              void* d_out, int out_size, void* d_ws, size_t ws_size,
                              hipStream_t stream) {
  const float* x  = (const float*)d_in[0];
  const float* Wq = (const float*)d_in[1];
  const float* bq = (const float*)d_in[2];
  const float* Wk = (const float*)d_in[3];
  const float* bk = (const float*)d_in[4];
  const float* Wv = (const float*)d_in[5];
  const float* bv = (const float*)d_in[6];
  const float* Wo = (const float*)d_in[7];
  const float* bo = (const float*)d_in[8];
  const float* relb = (const float*)d_in[9];

  uint8_t* ws = (uint8_t*)d_ws;
  ushort* x_bf   = (ushort*)(ws + 0);                    // 16 MB
  ushort* wq_bf  = (ushort*)(ws + (16u << 20));          // 2 MB each, contiguous (q,k,v,o)
  ushort* wk_bf  = (ushort*)(ws + (18u << 20));
  ushort* wv_bf  = (ushort*)(ws + (20u << 20));
  ushort* wo_bf  = (ushort*)(ws + (22u << 20));
  ushort* q_bf   = (ushort*)(ws + (24u << 20));          // 16 MB
  ushort* k_bf   = (ushort*)(ws + (40u << 20));          // 16 MB
  ushort* vt_bf  = (ushort*)(ws + (56u << 20));          // 16 MB
  ushort* at_bf  = (ushort*)(ws + (72u << 20));          // 16 MB
  (void)wk_bf; (void)wv_bf;

  const int NX = MM * DIM / 4;       // 2097152
  cast_kernel<<<NX / 256, 256, 0, stream>>>(x, x_bf, NX);
  cast4_kernel<<<(4 << 18) / 256, 256, 0, stream>>>(Wq, Wk, Wv, Wo, wq_bf);

  gemm_qkv<<<dim3(3 * DIM / 128, MM / 128), 256, 0, stream>>>(
      x_bf, wq_bf, bq, bk, bv, q_bf, k_bf, vt_bf);

  attn_kernel<<<dim3(SS / 64 * BB * NHEAD), 256, 0, stream>>>(q_bf, k_bf, vt_bf, relb, at_bf);

  gemm_bt<<<dim3(DIM / 128, MM / 128), 256, 0, stream>>>(at_bf, wo_bf, bo, (float*)d_out);
}